// Round 16
// baseline (177.131 us; speedup 1.0000x reference)
//
#include <hip/hip_runtime.h>
#include <hip/hip_bf16.h>

typedef __bf16 bf16;
typedef __attribute__((ext_vector_type(8))) __bf16 bf16x8;
typedef __attribute__((ext_vector_type(4))) __bf16 bf16x4;
typedef __attribute__((ext_vector_type(16))) float f32x16;
typedef unsigned long long u64;

#define N_ROWS 16384
#define DIM 256
#define NJC 512            /* 32-row tiles of A'' */
#define NBLKS 768          /* 3 blocks/CU x 256 CU = exact residency */
#define TPB 43             /* 33024 / 768 exactly */
#define NTILES 33024       /* sum_{it=0}^{127} (512-4it) */
#define TILE_ELEMS 8192    /* 32 rows x 256 cols per tile-stream */
#define SQK1 4.53981608f   /* sqrt(1/(0.07*ln2)): A pre-scaled so e^{z} = 2^{dot'} */
#define LN2F 0.69314718056f

#define WS_T_OFF (N_ROWS * DIM * 2)
#define WS_D_OFF (WS_T_OFF + N_ROWS * 4)

// Kernel 1: L2-normalize rows, scale by SQK1, emit bf16 A'' in FRAGMENT-
// STREAM layout: A''[tile][k][lane][8], where lane = hi*32+lo holds chunk
// (2k+hi) of row tile*32+lo. This is exactly the per-lane MFMA fragment
// order, so BOTH the loss kernel's B reads and af reloads are perfectly
// coalesced 16B/lane wave loads. Per-lane values are bit-identical to the
// champion's LDS path. Zeros T[] and d_out. Dg[row] = s2' =
// sum(bf16(SQK1*a)^2) = the MFMA diagonal, so the diagonal's bf16 rounding
// error cancels: loss_i = ln2*(log2(T'_i) - s2'_i).
__global__ void __launch_bounds__(256) normalize_kernel(const float* __restrict__ in,
                                                        bf16* __restrict__ out,
                                                        float* __restrict__ Tg,
                                                        float* __restrict__ Dg,
                                                        float* __restrict__ loss_out) {
    if (blockIdx.x == 0 && threadIdx.x == 0) loss_out[0] = 0.0f;
    if (blockIdx.x < 64) Tg[blockIdx.x * 256 + threadIdx.x] = 0.0f;

    const int row  = blockIdx.x * 4 + (threadIdx.x >> 6);
    const int lane = threadIdx.x & 63;
    const float4* rp = (const float4*)(in + (size_t)row * DIM);
    float4 v = rp[lane];
    float ss = v.x * v.x + v.y * v.y + v.z * v.z + v.w * v.w;
#pragma unroll
    for (int m = 1; m < 64; m <<= 1) ss += __shfl_xor(ss, m, 64);
    float inv = SQK1 / fmaxf(sqrtf(ss), 1e-12f);
    bf16x4 o;
    o[0] = (bf16)(v.x * inv);
    o[1] = (bf16)(v.y * inv);
    o[2] = (bf16)(v.z * inv);
    o[3] = (bf16)(v.w * inv);

    // lane holds source elements [lane*4, lane*4+4) of `row`:
    //   chunk c = lane>>1, half h = lane&1;  c = 2k+hi -> k = lane>>2,
    //   hi = (lane>>1)&1.  Stream slot l2 = hi*32 + (row&31).
    {
        const int tile = row >> 5, lo = row & 31;
        const int k  = lane >> 2;
        const int hi = (lane >> 1) & 1;
        const int h  = lane & 1;
        union { bf16x4 v4; u64 u; } pun;
        pun.v4 = o;
        *(u64*)(out + (size_t)tile * TILE_ELEMS + k * 512 + (hi * 32 + lo) * 8 + h * 4)
            = pun.u;
    }

    float f0 = (float)o[0], f1 = (float)o[1], f2 = (float)o[2], f3 = (float)o[3];
    float s2 = f0 * f0 + f1 * f1 + f2 * f2 + f3 * f3;
#pragma unroll
    for (int m = 1; m < 64; m <<= 1) s2 += __shfl_xor(s2, m, 64);
    if (lane == 0) Dg[row] = s2;
}

// Tree-reduce 16 floats across the 32 `lo` lanes; every lane ends with the
// full sum for register index r = (lo>>1)&15. (Correctness-proven R4-R10.)
#define TREE16(R, out)                                                     \
    do {                                                                   \
        float w8[8], w4[4], w2[2], w1, g_;                                 \
        _Pragma("unroll") for (int i_ = 0; i_ < 8; ++i_) {                 \
            g_ = (lo & 16) ? R[i_] : R[i_ + 8];                            \
            w8[i_] = ((lo & 16) ? R[i_ + 8] : R[i_]) + __shfl_xor(g_, 16); \
        }                                                                  \
        _Pragma("unroll") for (int i_ = 0; i_ < 4; ++i_) {                 \
            g_ = (lo & 8) ? w8[i_] : w8[i_ + 4];                           \
            w4[i_] = ((lo & 8) ? w8[i_ + 4] : w8[i_]) + __shfl_xor(g_, 8); \
        }                                                                  \
        _Pragma("unroll") for (int i_ = 0; i_ < 2; ++i_) {                 \
            g_ = (lo & 4) ? w4[i_] : w4[i_ + 2];                           \
            w2[i_] = ((lo & 4) ? w4[i_ + 2] : w4[i_]) + __shfl_xor(g_, 4); \
        }                                                                  \
        g_ = (lo & 2) ? w2[0] : w2[1];                                     \
        w1 = ((lo & 2) ? w2[1] : w2[0]) + __shfl_xor(g_, 2);               \
        out = w1 + __shfl_xor(w1, 1);                                      \
    } while (0)

// Kernel 2: symmetric A'A'^T + softmax denominator — NO LDS.
// R25 -> R26: drop the entire LDS staging apparatus (DMA, 2 barriers/tile,
// vmcnt discipline, 8.45M conflict cycles, 64KB LDS-read + 16KB LDS-write
// per block-tile). A' is 8MB = fully L3-resident; guide Common-mistake #7:
// staging cache-fitting data in LDS is pure overhead. The fragment-stream
// layout makes every access a perfectly coalesced 16B/lane wave load:
//   b fragment (tile jc, k):  A''[jc*8192 + k*512 + l*8], l = hi*32+lo
//   af (strip it, wave w):    A''[(it*4+w)*8192 + k*512 + l*8]
// (identical per-lane values to the champion -> identical math). 4 waves
// of a block read the same 16KB tile-stream -> L1 (32KB) serves the reuse;
// one raw s_barrier per tile (NO waitcnt attached) keeps waves phase-
// locked for L1 locality. Bandwidth floor: 33024 x 64KB / 256 CU at
// 64-128 B/cy/CU = 27-55 us vs champion's 85.5. No vmcnt discipline ->
// diagonal-tile col atomic is simply skipped.
__global__ void __launch_bounds__(256, 3)
loss_kernel(const bf16* __restrict__ A2, float* __restrict__ Tg) {
    const int tid = threadIdx.x;
    const int w  = tid >> 6;      // wave = row-group: rows w*32..+31 of the 128-row strip
    const int l  = tid & 63;
    const int lo = l & 31, hi = l >> 5;
    (void)hi;

    // flat tile range for this block: exactly TPB tiles
    const int tbeg = blockIdx.x * TPB;

    // decode starting (it, jc): C(it) = 2*it*(257-it) <= tbeg < C(it+1)
    int it = 0;
    while (2 * (it + 1) * (257 - (it + 1)) <= tbeg) ++it;
    int jc = 4 * it + (tbeg - 2 * it * (257 - it));

    // persistent A fragments: wave w's af IS the fragment stream of tile
    // (it*4 + w) — coalesced 16B/lane loads.
    bf16x8 af[16];
#define LOAD_AF(ITX)                                                         \
    do {                                                                     \
        const bf16* ap_ = A2 + (size_t)((ITX) * 4 + w) * TILE_ELEMS + l * 8; \
        _Pragma("unroll") for (int k_ = 0; k_ < 16; ++k_)                    \
            af[k_] = *(const bf16x8*)(ap_ + k_ * 512);                       \
    } while (0)
    LOAD_AF(it);

    float s0[16];
#pragma unroll
    for (int r = 0; r < 16; ++r) s0[r] = 0.f;

#define FLUSH_ROWS                                                           \
    do {                                                                     \
        float tr_;                                                           \
        TREE16(s0, tr_);                                                     \
        const int r_ = (lo >> 1) & 15;                                       \
        const int rowoff_ = (r_ & 3) + 8 * (r_ >> 2) + 4 * (l >> 5);         \
        if ((l & 1) == 0)                                                    \
            atomicAdd(&Tg[it * 128 + w * 32 + rowoff_], tr_);                \
    } while (0)

    for (int t = 0; t < TPB; ++t) {
        // pacing barrier only (no data through LDS, no waitcnt drain):
        // keeps the block's 4 waves on the same tile for L1 reuse.
        asm volatile("s_barrier" ::: "memory");

        const bf16* tb = A2 + (size_t)jc * TILE_ELEMS + l * 8;
        f32x16 c0;
#pragma unroll
        for (int r = 0; r < 16; ++r) c0[r] = 0.f;
#pragma unroll
        for (int k = 0; k < 16; ++k) {
            bf16x8 b = *(const bf16x8*)(tb + k * 512);
            c0 = __builtin_amdgcn_mfma_f32_32x32x16_bf16(af[k], b, c0, 0, 0, 0);
        }

        float cs = 0.f;
#pragma unroll
        for (int r = 0; r < 16; ++r) {
            float e = __builtin_amdgcn_exp2f(c0[r]);
            s0[r] += e;
            cs += e;
        }
        cs += __shfl_xor(cs, 32);
        // col-sum flush; skip the diagonal 128x128 block (jc>>2 == it):
        // its entries are fully covered by row sums.
        if (((jc >> 2) != it) && (l >> 5) == 0)
            atomicAdd(&Tg[jc * 32 + lo], cs);

        // advance; at strip boundary: flush row sums, reload af
        if (t + 1 < TPB) {
            if (++jc == NJC) {
                FLUSH_ROWS;
                ++it;
                jc = 4 * it;
                LOAD_AF(it);
#pragma unroll
                for (int r = 0; r < 16; ++r) s0[r] = 0.f;
            }
        }
    }
    FLUSH_ROWS;

#undef FLUSH_ROWS
#undef LOAD_AF
}

// Kernel 3: loss_i = ln2*(log2(T'_i) - s2'_i), mean over rows.
__global__ void __launch_bounds__(256) final_kernel(const float* __restrict__ Tg,
                                                    const float* __restrict__ Dg,
                                                    float* __restrict__ out) {
    __shared__ float red[4];
    const int i = blockIdx.x * 256 + threadIdx.x;
    float c = LN2F * (__log2f(Tg[i]) - Dg[i]) * (1.0f / (float)N_ROWS);
#pragma unroll
    for (int m = 1; m < 64; m <<= 1) c += __shfl_xor(c, m, 64);
    if ((threadIdx.x & 63) == 0) red[threadIdx.x >> 6] = c;
    __syncthreads();
    if (threadIdx.x == 0)
        atomicAdd(out, red[0] + red[1] + red[2] + red[3]);
}

extern "C" void kernel_launch(void* const* d_in, const int* in_sizes, int n_in,
                              void* d_out, int out_size, void* d_ws, size_t ws_size,
                              hipStream_t stream) {
    const float* emb = (const float*)d_in[0];
    float* out = (float*)d_out;
    bf16* Abf = (bf16*)d_ws;
    float* Tg = (float*)((char*)d_ws + WS_T_OFF);
    float* Dg = (float*)((char*)d_ws + WS_D_OFF);

    hipLaunchKernelGGL(normalize_kernel, dim3(N_ROWS / 4), dim3(256), 0, stream,
                       emb, Abf, Tg, Dg, out);
    hipLaunchKernelGGL(loss_kernel, dim3(NBLKS), dim3(256), 0, stream,
                       Abf, Tg);
    hipLaunchKernelGGL(final_kernel, dim3(N_ROWS / 256), dim3(256), 0, stream,
                       Tg, Dg, out);
}